// Round 1
// baseline (9506.845 us; speedup 1.0000x reference)
//
#include <hip/hip_runtime.h>
#include <hip/hip_bf16.h>
#include <math.h>

// Problem constants
#define BSZ 512
#define SEQL 32
#define EDIM 1024
#define HDIM 1024
#define MIDL 30

// ---------------------------------------------------------------------------
// h init: copy h0 (2,512,1024) into workspace h buffer
__global__ __launch_bounds__(256) void copy_h0_kernel(const float* __restrict__ h0,
                                                      float* __restrict__ hbuf) {
    int i = blockIdx.x * 256 + threadIdx.x;   // grid 4096 -> 1,048,576 exact
    hbuf[i] = h0[i];
}

// ---------------------------------------------------------------------------
// ua2[d][b][s][h] = sum_e x[b,s,e] * Ua[d,h,e]   (h in {0,1})
// one wave per (d,b,s) task; 2*512*32 = 32768 tasks; grid 8192 x 256 (4 waves)
__global__ __launch_bounds__(256) void ua2_kernel(const float* __restrict__ x,
                                                  const float* __restrict__ Ua,
                                                  float* __restrict__ ua2) {
    int task = blockIdx.x * 4 + (threadIdx.x >> 6);
    int lane = threadIdx.x & 63;
    int d = task >> 14;            // / (512*32)
    int rem = task & 16383;
    int b = rem >> 5, s = rem & 31;
    const float* xr = x + ((size_t)b * SEQL + s) * EDIM;
    const float* u  = Ua + (size_t)d * 2 * EDIM;
    float a0 = 0.f, a1 = 0.f;
    for (int e = lane; e < EDIM; e += 64) {
        float xv = xr[e];
        a0 += xv * u[e];
        a1 += xv * u[EDIM + e];
    }
    for (int off = 32; off > 0; off >>= 1) {
        a0 += __shfl_down(a0, off);
        a1 += __shfl_down(a1, off);
    }
    if (lane == 0) {
        float* o = ua2 + (size_t)task * 2;
        o[0] = a0; o[1] = a1;
    }
}

// ---------------------------------------------------------------------------
// GEMM1: out1[b, n] = [h | xs] @ [U* ; W*] rows.  n<1024 -> z gate, n>=1024 -> r gate
// Epilogue: z = sigmoid(acc) -> zbuf ;  r = sigmoid(acc), rh = r*h -> rhbuf
// xs generated on the fly: sum of 3 consecutive x rows (window start s0).
// Tile 64x64, BK=16, 256 threads, 4x4 per thread.
__global__ __launch_bounds__(256) void gemm1_zr(
    const float* __restrict__ hbuf, const float* __restrict__ x,
    const float* __restrict__ Uz, const float* __restrict__ Ur,
    const float* __restrict__ Wz, const float* __restrict__ Wr,
    float* __restrict__ zbuf, float* __restrict__ rhbuf, int m) {
    const int d  = blockIdx.z;
    const int b0 = blockIdx.x * 64;
    const int n0 = blockIdx.y * 64;
    const int tid = threadIdx.x;
    const int tx = tid & 15, ty = tid >> 4;

    __shared__ __align__(16) float As[16][68];
    __shared__ __align__(16) float Bs[16][68];

    float acc[4][4];
#pragma unroll
    for (int i = 0; i < 4; i++)
#pragma unroll
        for (int j = 0; j < 4; j++) acc[i][j] = 0.f;

    const int lrow = tid >> 2;        // 0..63
    const int lkq  = (tid & 3) * 4;   // 0,4,8,12

    const int s0 = (d == 0) ? m : (29 - m);       // window start (3 rows)
    const float* hb = hbuf + (size_t)d * BSZ * HDIM;

    const int rgate = (n0 >= 1024) ? 1 : 0;
    const int nrow0 = n0 - rgate * 1024;
    const float* Umat = (rgate ? Ur : Uz) + (size_t)d * HDIM * HDIM;
    const float* Wmat = (rgate ? Wr : Wz) + (size_t)d * HDIM * EDIM;

    for (int k0 = 0; k0 < 2048; k0 += 16) {
        float4 av;
        if (k0 < 1024) {
            av = *(const float4*)&hb[(size_t)(b0 + lrow) * HDIM + k0 + lkq];
        } else {
            const float* xr = x + ((size_t)(b0 + lrow) * SEQL + s0) * EDIM + (k0 - 1024 + lkq);
            float4 a0v = *(const float4*)(xr);
            float4 a1v = *(const float4*)(xr + EDIM);
            float4 a2v = *(const float4*)(xr + 2 * EDIM);
            av.x = a0v.x + a1v.x + a2v.x;
            av.y = a0v.y + a1v.y + a2v.y;
            av.z = a0v.z + a1v.z + a2v.z;
            av.w = a0v.w + a1v.w + a2v.w;
        }
        As[lkq + 0][lrow] = av.x; As[lkq + 1][lrow] = av.y;
        As[lkq + 2][lrow] = av.z; As[lkq + 3][lrow] = av.w;

        const float* wrow = (k0 < 1024)
            ? (Umat + (size_t)(nrow0 + lrow) * HDIM + k0 + lkq)
            : (Wmat + (size_t)(nrow0 + lrow) * EDIM + (k0 - 1024) + lkq);
        float4 bv = *(const float4*)wrow;
        Bs[lkq + 0][lrow] = bv.x; Bs[lkq + 1][lrow] = bv.y;
        Bs[lkq + 2][lrow] = bv.z; Bs[lkq + 3][lrow] = bv.w;

        __syncthreads();
#pragma unroll
        for (int k = 0; k < 16; k++) {
            float4 a = *(const float4*)&As[k][ty * 4];
            float4 b = *(const float4*)&Bs[k][tx * 4];
            float aa[4] = {a.x, a.y, a.z, a.w};
            float bb[4] = {b.x, b.y, b.z, b.w};
#pragma unroll
            for (int i = 0; i < 4; i++)
#pragma unroll
                for (int j = 0; j < 4; j++) acc[i][j] += aa[i] * bb[j];
        }
        __syncthreads();
    }

#pragma unroll
    for (int i = 0; i < 4; i++) {
        int b = b0 + ty * 4 + i;
#pragma unroll
        for (int j = 0; j < 4; j++) {
            int n = n0 + tx * 4 + j;
            float sg = 1.f / (1.f + expf(-acc[i][j]));
            if (!rgate) {
                zbuf[((size_t)d * BSZ + b) * HDIM + n] = sg;
            } else {
                int n2 = n - 1024;
                rhbuf[((size_t)d * BSZ + b) * HDIM + n2] = sg * hb[(size_t)b * HDIM + n2];
            }
        }
    }
}

// ---------------------------------------------------------------------------
// GEMM2: acc[b,n] = [rh | xs] @ [Uh ; Wh] rows; epilogue: hw = tanh(acc),
// h_new = (1-z)*h + z*hw  (written in place to hbuf)
__global__ __launch_bounds__(256) void gemm2_h(
    float* __restrict__ hbuf, const float* __restrict__ x,
    const float* __restrict__ rhbuf,
    const float* __restrict__ Uh, const float* __restrict__ Wh,
    const float* __restrict__ zbuf, int m) {
    const int d  = blockIdx.z;
    const int b0 = blockIdx.x * 64;
    const int n0 = blockIdx.y * 64;
    const int tid = threadIdx.x;
    const int tx = tid & 15, ty = tid >> 4;

    __shared__ __align__(16) float As[16][68];
    __shared__ __align__(16) float Bs[16][68];

    float acc[4][4];
#pragma unroll
    for (int i = 0; i < 4; i++)
#pragma unroll
        for (int j = 0; j < 4; j++) acc[i][j] = 0.f;

    const int lrow = tid >> 2;
    const int lkq  = (tid & 3) * 4;

    const int s0 = (d == 0) ? m : (29 - m);
    const float* rb = rhbuf + (size_t)d * BSZ * HDIM;
    const float* Umat = Uh + (size_t)d * HDIM * HDIM;
    const float* Wmat = Wh + (size_t)d * HDIM * EDIM;

    for (int k0 = 0; k0 < 2048; k0 += 16) {
        float4 av;
        if (k0 < 1024) {
            av = *(const float4*)&rb[(size_t)(b0 + lrow) * HDIM + k0 + lkq];
        } else {
            const float* xr = x + ((size_t)(b0 + lrow) * SEQL + s0) * EDIM + (k0 - 1024 + lkq);
            float4 a0v = *(const float4*)(xr);
            float4 a1v = *(const float4*)(xr + EDIM);
            float4 a2v = *(const float4*)(xr + 2 * EDIM);
            av.x = a0v.x + a1v.x + a2v.x;
            av.y = a0v.y + a1v.y + a2v.y;
            av.z = a0v.z + a1v.z + a2v.z;
            av.w = a0v.w + a1v.w + a2v.w;
        }
        As[lkq + 0][lrow] = av.x; As[lkq + 1][lrow] = av.y;
        As[lkq + 2][lrow] = av.z; As[lkq + 3][lrow] = av.w;

        const float* wrow = (k0 < 1024)
            ? (Umat + (size_t)(n0 + lrow) * HDIM + k0 + lkq)
            : (Wmat + (size_t)(n0 + lrow) * EDIM + (k0 - 1024) + lkq);
        float4 bv = *(const float4*)wrow;
        Bs[lkq + 0][lrow] = bv.x; Bs[lkq + 1][lrow] = bv.y;
        Bs[lkq + 2][lrow] = bv.z; Bs[lkq + 3][lrow] = bv.w;

        __syncthreads();
#pragma unroll
        for (int k = 0; k < 16; k++) {
            float4 a = *(const float4*)&As[k][ty * 4];
            float4 b = *(const float4*)&Bs[k][tx * 4];
            float aa[4] = {a.x, a.y, a.z, a.w};
            float bb[4] = {b.x, b.y, b.z, b.w};
#pragma unroll
            for (int i = 0; i < 4; i++)
#pragma unroll
                for (int j = 0; j < 4; j++) acc[i][j] += aa[i] * bb[j];
        }
        __syncthreads();
    }

    float* hb = hbuf + (size_t)d * BSZ * HDIM;
#pragma unroll
    for (int i = 0; i < 4; i++) {
        int b = b0 + ty * 4 + i;
#pragma unroll
        for (int j = 0; j < 4; j++) {
            int n = n0 + tx * 4 + j;
            float hw = tanhf(acc[i][j]);
            size_t idx = ((size_t)d * BSZ + b) * HDIM + n;
            float z = zbuf[idx];
            float hv = hb[(size_t)b * HDIM + n];
            hb[(size_t)b * HDIM + n] = hv + z * (hw - hv);
        }
    }
}

// ---------------------------------------------------------------------------
// Attention for step m: per (d,b): wa[g,h]=h . Wa_w[h,g,:], et, softmax(3), out row
__global__ __launch_bounds__(256) void attn_step(
    const float* __restrict__ hbuf, const float* __restrict__ x,
    const float* __restrict__ ua2,
    const float* __restrict__ Wa_w, const float* __restrict__ Wa_b,
    const float* __restrict__ fh_w, const float* __restrict__ fh_b,
    float* __restrict__ Xbuf, int m) {
    const int blk = blockIdx.x;
    const int d = blk >> 9;
    const int b = blk & 511;
    const int tid = threadIdx.x;

    const float* hb = hbuf + ((size_t)d * BSZ + b) * HDIM;
    const float* Ww = Wa_w + (size_t)d * 2 * 3 * HDIM;   // [h2][g][j], q = h2*3+g

    float w[6] = {0.f, 0.f, 0.f, 0.f, 0.f, 0.f};
    for (int j = tid; j < HDIM; j += 256) {
        float hv = hb[j];
#pragma unroll
        for (int q = 0; q < 6; q++) w[q] += hv * Ww[(size_t)q * HDIM + j];
    }

    __shared__ float sred[256][6];
#pragma unroll
    for (int q = 0; q < 6; q++) sred[tid][q] = w[q];
    __syncthreads();
    for (int s = 128; s > 0; s >>= 1) {
        if (tid < s) {
#pragma unroll
            for (int q = 0; q < 6; q++) sred[tid][q] += sred[tid + s][q];
        }
        __syncthreads();
    }

    int p[3];
#pragma unroll
    for (int g = 0; g < 3; g++) p[g] = (d == 0) ? (m + g) : (31 - m - g);

    const float fw0 = fh_w[d * 2 + 0], fw1 = fh_w[d * 2 + 1], fbv = fh_b[d];
    float et[3];
#pragma unroll
    for (int g = 0; g < 3; g++) {
        const float* u = ua2 + (((size_t)d * BSZ + b) * SEQL + p[g]) * 2;
        float a0 = u[0] + sred[0][0 + g] + Wa_b[d * 6 + 0 + g];
        float a1 = u[1] + sred[0][3 + g] + Wa_b[d * 6 + 3 + g];
        et[g] = tanhf(a0 * fw0 + a1 * fw1 + fbv);
    }
    float mx = fmaxf(et[0], fmaxf(et[1], et[2]));
    float e0 = expf(et[0] - mx), e1 = expf(et[1] - mx), e2 = expf(et[2] - mx);
    float inv = 1.f / (e0 + e1 + e2);
    float al0 = e0 * inv, al1 = e1 * inv, al2 = e2 * inv;

    const float* xb = x + (size_t)b * SEQL * EDIM;
    float* Xo = Xbuf + (((size_t)d * BSZ + b) * MIDL + m) * EDIM;
    for (int e = tid; e < EDIM; e += 256) {
        Xo[e] = al0 * xb[(size_t)p[0] * EDIM + e]
              + al1 * xb[(size_t)p[1] * EDIM + e]
              + al2 * xb[(size_t)p[2] * EDIM + e];
    }
}

// ---------------------------------------------------------------------------
// Final mix: out[b,mo,e] = sum_{j=0..59} fb_w[mo,j] * Xcat[b,j,e] + fb_b[mo]
__global__ __launch_bounds__(256) void final_mix(
    const float* __restrict__ Xbuf, const float* __restrict__ fbw,
    const float* __restrict__ fbb, float* __restrict__ out) {
    __shared__ float sw[30][60];
    __shared__ float sb[30];
    const int tid = threadIdx.x;
    for (int i = tid; i < 1800; i += 256) sw[i / 60][i % 60] = fbw[i];
    if (tid < 30) sb[tid] = fbb[tid];
    __syncthreads();

    const int idx = blockIdx.x * 256 + tid;   // 0 .. 524287
    const int b = idx >> 10;
    const int e = idx & 1023;

    float acc[30];
#pragma unroll
    for (int mo = 0; mo < 30; mo++) acc[mo] = sb[mo];

    for (int d = 0; d < 2; d++) {
        for (int mm = 0; mm < 30; mm++) {
            float v = Xbuf[(((size_t)d * BSZ + b) * MIDL + mm) * EDIM + e];
            int j = d * 30 + mm;
#pragma unroll
            for (int mo = 0; mo < 30; mo++) acc[mo] += sw[mo][j] * v;
        }
    }
    float* ob = out + (size_t)b * 30 * EDIM;
#pragma unroll
    for (int mo = 0; mo < 30; mo++) ob[(size_t)mo * EDIM + e] = acc[mo];
}

// ---------------------------------------------------------------------------
extern "C" void kernel_launch(void* const* d_in, const int* in_sizes, int n_in,
                              void* d_out, int out_size, void* d_ws, size_t ws_size,
                              hipStream_t stream) {
    const float* x    = (const float*)d_in[0];
    const float* h0   = (const float*)d_in[1];
    const float* Wz   = (const float*)d_in[2];
    const float* Uz   = (const float*)d_in[3];
    const float* Wr   = (const float*)d_in[4];
    const float* Ur   = (const float*)d_in[5];
    const float* Wh   = (const float*)d_in[6];
    const float* Uh   = (const float*)d_in[7];
    const float* Ua   = (const float*)d_in[8];
    const float* Wa_w = (const float*)d_in[9];
    const float* Wa_b = (const float*)d_in[10];
    const float* fh_w = (const float*)d_in[11];
    const float* fh_b = (const float*)d_in[12];
    const float* fb_w = (const float*)d_in[13];
    const float* fb_b = (const float*)d_in[14];
    float* out = (float*)d_out;

    float* ws    = (float*)d_ws;
    float* hbuf  = ws;                       // 2*512*1024      = 1,048,576 f
    float* zbuf  = hbuf  + 1048576;          // 1,048,576 f
    float* rhbuf = zbuf  + 1048576;          // 1,048,576 f
    float* ua2   = rhbuf + 1048576;          // 2*512*32*2      = 65,536 f
    float* Xbuf  = ua2   + 65536;            // 2*512*30*1024   = 31,457,280 f
    // total ~138.7 MB

    copy_h0_kernel<<<4096, 256, 0, stream>>>(h0, hbuf);
    ua2_kernel<<<8192, 256, 0, stream>>>(x, Ua, ua2);

    for (int m = 0; m < MIDL; m++) {
        gemm1_zr<<<dim3(8, 32, 2), 256, 0, stream>>>(hbuf, x, Uz, Ur, Wz, Wr, zbuf, rhbuf, m);
        attn_step<<<1024, 256, 0, stream>>>(hbuf, x, ua2, Wa_w, Wa_b, fh_w, fh_b, Xbuf, m);
        gemm2_h<<<dim3(8, 16, 2), 256, 0, stream>>>(hbuf, x, rhbuf, Uh, Wh, zbuf, m);
    }

    final_mix<<<2048, 256, 0, stream>>>(Xbuf, fb_w, fb_b, out);
}

// Round 2
// 5045.352 us; speedup vs baseline: 1.8843x; 1.8843x over previous
//
#include <hip/hip_runtime.h>
#include <hip/hip_bf16.h>
#include <math.h>

#define BSZ 512
#define SEQL 32
#define EDIM 1024
#define HDIM 1024
#define MIDL 30

typedef unsigned short u16;
typedef __attribute__((ext_vector_type(8))) short bf16x8_t;   // 8 bf16 in 4 VGPRs
typedef __attribute__((ext_vector_type(4))) float floatx4_t;  // MFMA accumulator

// round-to-nearest bf16 split: v ~= hi + lo (each bf16), err ~2^-17 rel
__device__ inline u16 f2bf(float v) {
    unsigned u = __float_as_uint(v);
    unsigned r = u + 0x7FFFu + ((u >> 16) & 1u);
    return (u16)(r >> 16);
}
__device__ inline float bf2f(u16 h) { return __uint_as_float(((unsigned)h) << 16); }
__device__ inline void split2(float v, u16& hi, u16& lo) {
    u16 h = f2bf(v);
    hi = h;
    lo = f2bf(v - bf2f(h));
}

// LDS swizzle: row stride 128B, XOR row into 16B-slot bits (conflict-free b128)
#define SWZ(r, cb) (((r) << 7) + ((cb) ^ (((r) & 7) << 4)))

// ---------------------------------------------------------------------------
// weight fp32 -> bf16 hi/lo (2M elems per matrix), grid 2048x256, vec4
__global__ __launch_bounds__(256) void convert_w(const float* __restrict__ src,
                                                 u16* __restrict__ hi,
                                                 u16* __restrict__ lo,
                                                 int writeLo) {
    size_t i = ((size_t)blockIdx.x * 256 + threadIdx.x) * 4;
    float4 v = *(const float4*)(src + i);
    u16 hx, lx, hy, ly, hz, lz, hw, lw;
    split2(v.x, hx, lx); split2(v.y, hy, ly);
    split2(v.z, hz, lz); split2(v.w, hw, lw);
    ushort4 hv; hv.x = hx; hv.y = hy; hv.z = hz; hv.w = hw;
    *(ushort4*)(hi + i) = hv;
    if (writeLo) {
        ushort4 lv; lv.x = lx; lv.y = ly; lv.z = lz; lv.w = lw;
        *(ushort4*)(lo + i) = lv;
    }
}

// ---------------------------------------------------------------------------
// h0 -> hbuf fp32 + h hi/lo bf16, grid 1024x256, vec4 (1,048,576 elems)
__global__ __launch_bounds__(256) void init_h(const float* __restrict__ h0,
                                              float* __restrict__ hbuf,
                                              u16* __restrict__ hhi,
                                              u16* __restrict__ hlo) {
    size_t i = ((size_t)blockIdx.x * 256 + threadIdx.x) * 4;
    float4 v = *(const float4*)(h0 + i);
    *(float4*)(hbuf + i) = v;
    u16 hx, lx, hy, ly, hz, lz, hw, lw;
    split2(v.x, hx, lx); split2(v.y, hy, ly);
    split2(v.z, hz, lz); split2(v.w, hw, lw);
    ushort4 hv; hv.x = hx; hv.y = hy; hv.z = hz; hv.w = hw;
    ushort4 lv; lv.x = lx; lv.y = ly; lv.z = lz; lv.w = lw;
    *(ushort4*)(hhi + i) = hv;
    *(ushort4*)(hlo + i) = lv;
}

// ---------------------------------------------------------------------------
// xs_win[b][w][e] = x[b][w][e]+x[b][w+1][e]+x[b][w+2][e] -> bf16 hi/lo
// grid 15360x256, vec4 (15,728,640 elems)
__global__ __launch_bounds__(256) void xs_build(const float* __restrict__ x,
                                                u16* __restrict__ xshi,
                                                u16* __restrict__ xslo,
                                                int writeLo) {
    int idx = blockIdx.x * 256 + threadIdx.x;  // 0..3,932,159
    int vid = idx & 255;                        // 256 vec4 per (b,w)
    int bw = idx >> 8;
    int w = bw % 30, b = bw / 30;
    const float* s = x + ((size_t)b * SEQL + w) * EDIM + vid * 4;
    float4 a = *(const float4*)s;
    float4 c = *(const float4*)(s + EDIM);
    float4 e = *(const float4*)(s + 2 * EDIM);
    float4 v; v.x = a.x + c.x + e.x; v.y = a.y + c.y + e.y;
    v.z = a.z + c.z + e.z; v.w = a.w + c.w + e.w;
    size_t o = ((size_t)b * 30 + w) * EDIM + vid * 4;
    u16 hx, lx, hy, ly, hz, lz, hw, lw;
    split2(v.x, hx, lx); split2(v.y, hy, ly);
    split2(v.z, hz, lz); split2(v.w, hw, lw);
    ushort4 hv; hv.x = hx; hv.y = hy; hv.z = hz; hv.w = hw;
    *(ushort4*)(xshi + o) = hv;
    if (writeLo) {
        ushort4 lv; lv.x = lx; lv.y = ly; lv.z = lz; lv.w = lw;
        *(ushort4*)(xslo + o) = lv;
    }
}

// ---------------------------------------------------------------------------
// ua2[d][b][s][h2] = sum_e x[b,s,e]*Ua[d,h2,e]; one block per (b,s), grid 16384
__global__ __launch_bounds__(256) void ua2_kernel(const float* __restrict__ x,
                                                  const float* __restrict__ Ua,
                                                  float* __restrict__ ua2) {
    int bs = blockIdx.x;
    int b = bs >> 5, s = bs & 31;
    const float* xr = x + ((size_t)b * SEQL + s) * EDIM;
    int tid = threadIdx.x;
    float a[4] = {0.f, 0.f, 0.f, 0.f};  // q = d*2+h2
    for (int e = tid; e < EDIM; e += 256) {
        float xv = xr[e];
#pragma unroll
        for (int q = 0; q < 4; q++) a[q] += xv * Ua[q * EDIM + e];
    }
#pragma unroll
    for (int q = 0; q < 4; q++)
        for (int off = 32; off > 0; off >>= 1) a[q] += __shfl_down(a[q], off);
    __shared__ float sr[4][4];
    int wid = tid >> 6, lane = tid & 63;
    if (lane == 0) {
#pragma unroll
        for (int q = 0; q < 4; q++) sr[wid][q] = a[q];
    }
    __syncthreads();
    if (tid < 4) {
        float v = sr[0][tid] + sr[1][tid] + sr[2][tid] + sr[3][tid];
        int d = tid >> 1, h2 = tid & 1;
        ua2[(((size_t)d * BSZ + b) * SEQL + s) * 2 + h2] = v;
    }
}

// ---------------------------------------------------------------------------
// Fused per-step GEMM (bf16x3 MFMA) + (MODE0) attention.
// MODE0: A=[h|xs], B=[Uz|Wz] / [Ur|Wr]; epi: z=sigmoid -> zbuf ; r -> rh hi/lo
//        blockIdx.y >= 2048/BN -> attention path (reads h, writes Xbuf)
// MODE1: A=[rh|xs], B=[Uh|Wh]; epi: h' = h + z*(tanh-h) -> hbuf + h hi/lo
template<int BN, int MODE, typename XT>
__global__ __launch_bounds__(256) void gemm_step(
    const u16* __restrict__ whi, const u16* __restrict__ wlo,
    const u16* __restrict__ ahi, const u16* __restrict__ alo,
    const u16* __restrict__ xshi, const u16* __restrict__ xslo,
    float* __restrict__ hbuf, float* __restrict__ zbuf,
    u16* __restrict__ ohi, u16* __restrict__ olo,
    const float* __restrict__ x, const float* __restrict__ ua2,
    const float* __restrict__ Wa_w, const float* __restrict__ Wa_b,
    const float* __restrict__ fh_w, const float* __restrict__ fh_b,
    XT* __restrict__ Xbuf,
    int m, int useXsLo, int useWLo) {

    __shared__ u16 AsHi[64 * 64], AsLo[64 * 64];
    __shared__ u16 BsHi[BN * 64], BsLo[BN * 64];
    __shared__ float sred[4][6];

    const int d = blockIdx.z;
    const int tid = threadIdx.x;
    const int wid = tid >> 6, lane = tid & 63;

    if (MODE == 0 && blockIdx.y >= (2048 / BN)) {
        // ------------------- attention path -------------------
        const int b = blockIdx.x * 64 + (blockIdx.y - (2048 / BN));
        const float* hb = hbuf + ((size_t)d * BSZ + b) * HDIM;
        const float* Ww = Wa_w + (size_t)d * 6 * HDIM;
        float w6[6] = {0.f, 0.f, 0.f, 0.f, 0.f, 0.f};
        for (int j = tid; j < HDIM; j += 256) {
            float hv = hb[j];
#pragma unroll
            for (int q = 0; q < 6; q++) w6[q] += hv * Ww[q * HDIM + j];
        }
#pragma unroll
        for (int q = 0; q < 6; q++)
            for (int off = 32; off > 0; off >>= 1) w6[q] += __shfl_down(w6[q], off);
        if (lane == 0) {
#pragma unroll
            for (int q = 0; q < 6; q++) sred[wid][q] = w6[q];
        }
        __syncthreads();
        float s6[6];
#pragma unroll
        for (int q = 0; q < 6; q++)
            s6[q] = sred[0][q] + sred[1][q] + sred[2][q] + sred[3][q];

        int p0 = (d == 0) ? m : (31 - m);
        int p1 = (d == 0) ? (m + 1) : (30 - m);
        int p2 = (d == 0) ? (m + 2) : (29 - m);
        const float fw0 = fh_w[d * 2 + 0], fw1 = fh_w[d * 2 + 1], fbv = fh_b[d];
        float et[3];
        int pg[3] = {p0, p1, p2};
#pragma unroll
        for (int g = 0; g < 3; g++) {
            const float* u = ua2 + (((size_t)d * BSZ + b) * SEQL + pg[g]) * 2;
            float a0 = u[0] + s6[g] + Wa_b[d * 6 + g];
            float a1 = u[1] + s6[3 + g] + Wa_b[d * 6 + 3 + g];
            et[g] = tanhf(a0 * fw0 + a1 * fw1 + fbv);
        }
        float mx = fmaxf(et[0], fmaxf(et[1], et[2]));
        float e0 = expf(et[0] - mx), e1 = expf(et[1] - mx), e2 = expf(et[2] - mx);
        float inv = 1.f / (e0 + e1 + e2);
        float al0 = e0 * inv, al1 = e1 * inv, al2 = e2 * inv;

        const float* xb = x + (size_t)b * SEQL * EDIM;
        int e4 = tid * 4;
        float4 x0 = *(const float4*)(xb + (size_t)p0 * EDIM + e4);
        float4 x1 = *(const float4*)(xb + (size_t)p1 * EDIM + e4);
        float4 x2 = *(const float4*)(xb + (size_t)p2 * EDIM + e4);
        float4 v; v.x = al0 * x0.x + al1 * x1.x + al2 * x2.x;
        v.y = al0 * x0.y + al1 * x1.y + al2 * x2.y;
        v.z = al0 * x0.z + al1 * x1.z + al2 * x2.z;
        v.w = al0 * x0.w + al1 * x1.w + al2 * x2.w;
        XT* Xo = Xbuf + (((size_t)d * BSZ + b) * MIDL + m) * EDIM + e4;
        if constexpr (sizeof(XT) == 4) {
            *(float4*)Xo = v;
        } else {
            ushort4 uv; uv.x = f2bf(v.x); uv.y = f2bf(v.y);
            uv.z = f2bf(v.z); uv.w = f2bf(v.w);
            *(ushort4*)Xo = uv;
        }
        return;
    }

    // ------------------- GEMM path -------------------
    const int b0 = blockIdx.x * 64;
    const int n0 = blockIdx.y * BN;
    const int w = (d == 0) ? m : (29 - m);

    int rgate, nrow0, matU, matW;
    if (MODE == 0) {
        rgate = (n0 >= 1024) ? 1 : 0;
        nrow0 = n0 & 1023;
        matU = rgate ? 1 : 0;   // Uz=0, Ur=1
        matW = rgate ? 4 : 3;   // Wz=3, Wr=4
    } else {
        rgate = 0; nrow0 = n0; matU = 2; matW = 5;  // Uh=2, Wh=5
    }

    floatx4_t acc[2][BN / 32];
#pragma unroll
    for (int i = 0; i < 2; i++)
#pragma unroll
        for (int j = 0; j < BN / 32; j++) acc[i][j] = (floatx4_t){0.f, 0.f, 0.f, 0.f};

    const int srow = tid >> 3;         // 0..31
    const int skb = (tid & 7) * 8;     // bf16 col in BK=64
    const int wm = wid >> 1, wn = wid & 1;

    for (int k0 = 0; k0 < 2048; k0 += 64) {
        const bool hp = (k0 < 1024);
        const int kc = hp ? k0 : (k0 - 1024);
        const u16* aH = hp ? ahi : xshi;
        const u16* aL = hp ? alo : xslo;
        const size_t wOff = (size_t)(hp ? matU : matW) * 2097152 + (size_t)d * 1048576;
        const u16* bH = whi + wOff;
        const u16* bL = wlo + wOff;

        __syncthreads();
#pragma unroll
        for (int p = 0; p < 2; p++) {
            int row = srow + 32 * p;
            size_t gi = hp ? (((size_t)d * BSZ + b0 + row) * 1024 + kc + skb)
                           : (((size_t)(b0 + row) * 30 + w) * 1024 + kc + skb);
            uint4 vh = *(const uint4*)(aH + gi);
            uint4 vl;
            if (hp || useXsLo) vl = *(const uint4*)(aL + gi);
            else vl = make_uint4(0, 0, 0, 0);
            int la = SWZ(row, skb * 2) >> 1;
            *(uint4*)(AsHi + la) = vh;
            *(uint4*)(AsLo + la) = vl;
        }
#pragma unroll
        for (int p = 0; p < BN / 32; p++) {
            int row = srow + 32 * p;
            size_t gi = (size_t)(nrow0 + row) * 1024 + kc + skb;
            uint4 vh = *(const uint4*)(bH + gi);
            uint4 vl;
            if (useWLo) vl = *(const uint4*)(bL + gi);
            else vl = make_uint4(0, 0, 0, 0);
            int la = SWZ(row, skb * 2) >> 1;
            *(uint4*)(BsHi + la) = vh;
            *(uint4*)(BsLo + la) = vl;
        }
        __syncthreads();

#pragma unroll
        for (int cc = 0; cc < 2; cc++) {
            bf16x8_t ah_[2], al_[2], bh_[BN / 32], bl_[BN / 32];
            const int cbyte = cc * 64 + ((lane >> 4) << 4);
#pragma unroll
            for (int mf = 0; mf < 2; mf++) {
                int r = wm * 32 + mf * 16 + (lane & 15);
                int ia = SWZ(r, cbyte) >> 1;
                ah_[mf] = *(const bf16x8_t*)(AsHi + ia);
                al_[mf] = *(const bf16x8_t*)(AsLo + ia);
            }
#pragma unroll
            for (int nf = 0; nf < BN / 32; nf++) {
                int r = wn * (BN / 2) + nf * 16 + (lane & 15);
                int ib = SWZ(r, cbyte) >> 1;
                bh_[nf] = *(const bf16x8_t*)(BsHi + ib);
                bl_[nf] = *(const bf16x8_t*)(BsLo + ib);
            }
#pragma unroll
            for (int mf = 0; mf < 2; mf++)
#pragma unroll
                for (int nf = 0; nf < BN / 32; nf++) {
                    acc[mf][nf] = __builtin_amdgcn_mfma_f32_16x16x32_bf16(
                        ah_[mf], bh_[nf], acc[mf][nf], 0, 0, 0);
                    acc[mf][nf] = __builtin_amdgcn_mfma_f32_16x16x32_bf16(
                        ah_[mf], bl_[nf], acc[mf][nf], 0, 0, 0);
                    acc[mf][nf] = __builtin_amdgcn_mfma_f32_16x16x32_bf16(
                        al_[mf], bh_[nf], acc[mf][nf], 0, 0, 0);
                }
        }
    }

    // epilogue: C/D layout col=lane&15, row=(lane>>4)*4+j
#pragma unroll
    for (int mf = 0; mf < 2; mf++)
#pragma unroll
        for (int nf = 0; nf < BN / 32; nf++)
#pragma unroll
            for (int j = 0; j < 4; j++) {
                int bb = b0 + wm * 32 + mf * 16 + ((lane >> 4) << 2) + j;
                int nn = nrow0 + wn * (BN / 2) + nf * 16 + (lane & 15);
                size_t oi = ((size_t)d * BSZ + bb) * 1024 + nn;
                float v = acc[mf][nf][j];
                if (MODE == 0) {
                    float sg = 1.f / (1.f + expf(-v));
                    if (!rgate) {
                        zbuf[oi] = sg;
                    } else {
                        float rh = sg * hbuf[oi];
                        u16 h, l; split2(rh, h, l);
                        ohi[oi] = h; olo[oi] = l;
                    }
                } else {
                    float hw = tanhf(v);
                    float z = zbuf[oi], hv = hbuf[oi];
                    float hn = hv + z * (hw - hv);
                    hbuf[oi] = hn;
                    u16 h, l; split2(hn, h, l);
                    ohi[oi] = h; olo[oi] = l;
                }
            }
}

// ---------------------------------------------------------------------------
// out[b,mo,e] = sum_j fb_w[mo,j]*Xcat[b,j,e] + fb_b[mo]
template<typename XT>
__global__ __launch_bounds__(256) void final_mix(const XT* __restrict__ Xbuf,
                                                 const float* __restrict__ fbw,
                                                 const float* __restrict__ fbb,
                                                 float* __restrict__ out) {
    __shared__ float sw[30][60];
    __shared__ float sb[30];
    const int tid = threadIdx.x;
    for (int i = tid; i < 1800; i += 256) sw[i / 60][i % 60] = fbw[i];
    if (tid < 30) sb[tid] = fbb[tid];
    __syncthreads();

    const int idx = blockIdx.x * 256 + tid;
    const int b = idx >> 10;
    const int e = idx & 1023;

    float accv[30];
#pragma unroll
    for (int mo = 0; mo < 30; mo++) accv[mo] = sb[mo];

    for (int dd = 0; dd < 2; dd++)
        for (int mm = 0; mm < 30; mm++) {
            float v;
            if constexpr (sizeof(XT) == 4)
                v = ((const float*)Xbuf)[(((size_t)dd * BSZ + b) * MIDL + mm) * EDIM + e];
            else
                v = bf2f(((const u16*)Xbuf)[(((size_t)dd * BSZ + b) * MIDL + mm) * EDIM + e]);
            int j = dd * 30 + mm;
#pragma unroll
            for (int mo = 0; mo < 30; mo++) accv[mo] += sw[mo][j] * v;
        }
    float* ob = out + (size_t)b * 30 * EDIM;
#pragma unroll
    for (int mo = 0; mo < 30; mo++) ob[(size_t)mo * EDIM + e] = accv[mo];
}

// ---------------------------------------------------------------------------
template<typename XT>
static void run_all(const float* x, const float* h0,
                    const float* Wz, const float* Uz, const float* Wr, const float* Ur,
                    const float* Wh, const float* Uh, const float* Ua,
                    const float* Wa_w, const float* Wa_b,
                    const float* fh_w, const float* fh_b,
                    const float* fb_w, const float* fb_b,
                    float* out,
                    float* hbuf, float* zbuf, float* ua2,
                    u16* whi, u16* wlo, u16* xshi, u16* xslo,
                    u16* hhi, u16* hlo, u16* rhhi, u16* rhlo,
                    XT* Xbuf, int useXsLo, int useWLo, hipStream_t stream) {
    // weight conversions: Uz=0, Ur=1, Uh=2, Wz=3, Wr=4, Wh=5
    convert_w<<<2048, 256, 0, stream>>>(Uz, whi + 0 * 2097152, wlo + 0 * 2097152, useWLo);
    convert_w<<<2048, 256, 0, stream>>>(Ur, whi + 1 * 2097152, wlo + 1 * 2097152, useWLo);
    convert_w<<<2048, 256, 0, stream>>>(Uh, whi + 2 * 2097152, wlo + 2 * 2097152, useWLo);
    convert_w<<<2048, 256, 0, stream>>>(Wz, whi + 3 * 2097152, wlo + 3 * 2097152, useWLo);
    convert_w<<<2048, 256, 0, stream>>>(Wr, whi + 4 * 2097152, wlo + 4 * 2097152, useWLo);
    convert_w<<<2048, 256, 0, stream>>>(Wh, whi + 5 * 2097152, wlo + 5 * 2097152, useWLo);
    init_h<<<1024, 256, 0, stream>>>(h0, hbuf, hhi, hlo);
    ua2_kernel<<<16384, 256, 0, stream>>>(x, Ua, ua2);
    xs_build<<<15360, 256, 0, stream>>>(x, xshi, xslo, useXsLo);

    for (int m = 0; m < MIDL; m++) {
        gemm_step<128, 0, XT><<<dim3(8, 16 + 64, 2), 256, 0, stream>>>(
            whi, wlo, hhi, hlo, xshi, xslo, hbuf, zbuf, rhhi, rhlo,
            x, ua2, Wa_w, Wa_b, fh_w, fh_b, Xbuf, m, useXsLo, useWLo);
        gemm_step<64, 1, XT><<<dim3(8, 16, 2), 256, 0, stream>>>(
            whi, wlo, rhhi, rhlo, xshi, xslo, hbuf, zbuf, hhi, hlo,
            x, ua2, Wa_w, Wa_b, fh_w, fh_b, Xbuf, m, useXsLo, useWLo);
    }
    final_mix<XT><<<2048, 256, 0, stream>>>(Xbuf, fb_w, fb_b, out);
}

extern "C" void kernel_launch(void* const* d_in, const int* in_sizes, int n_in,
                              void* d_out, int out_size, void* d_ws, size_t ws_size,
                              hipStream_t stream) {
    const float* x    = (const float*)d_in[0];
    const float* h0   = (const float*)d_in[1];
    const float* Wz   = (const float*)d_in[2];
    const float* Uz   = (const float*)d_in[3];
    const float* Wr   = (const float*)d_in[4];
    const float* Ur   = (const float*)d_in[5];
    const float* Wh   = (const float*)d_in[6];
    const float* Uh   = (const float*)d_in[7];
    const float* Ua   = (const float*)d_in[8];
    const float* Wa_w = (const float*)d_in[9];
    const float* Wa_b = (const float*)d_in[10];
    const float* fh_w = (const float*)d_in[11];
    const float* fh_b = (const float*)d_in[12];
    const float* fb_w = (const float*)d_in[13];
    const float* fb_b = (const float*)d_in[14];
    float* out = (float*)d_out;

    // tier selection by workspace size
    const size_t NEED1 = 256114688;   // fp32 Xbuf, full lo buffers
    const size_t NEED2 = 193200128;   // bf16 Xbuf, full lo buffers
    int useWLo = 1, useXsLo = 1;
    bool xf32 = (ws_size >= NEED1);
    bool tier3 = (!xf32 && ws_size < NEED2);
    if (tier3) { useWLo = 0; useXsLo = 0; }

    char* p = (char*)d_ws;
    auto take = [&](size_t n) { char* r = p; p += n; return r; };
    float* hbuf = (float*)take(4194304);
    float* zbuf = (float*)take(4194304);
    float* ua2  = (float*)take(262144);
    u16* whi  = (u16*)take(25165824);
    u16* wlo  = useWLo ? (u16*)take(25165824) : whi;
    u16* xshi = (u16*)take(31457280);
    u16* xslo = useXsLo ? (u16*)take(31457280) : xshi;
    u16* hhi  = (u16*)take(2097152);
    u16* hlo  = (u16*)take(2097152);
    u16* rhhi = (u16*)take(2097152);
    u16* rhlo = (u16*)take(2097152);

    if (xf32) {
        float* Xbuf = (float*)take(125829120);
        run_all<float>(x, h0, Wz, Uz, Wr, Ur, Wh, Uh, Ua, Wa_w, Wa_b, fh_w, fh_b,
                       fb_w, fb_b, out, hbuf, zbuf, ua2, whi, wlo, xshi, xslo,
                       hhi, hlo, rhhi, rhlo, Xbuf, useXsLo, useWLo, stream);
    } else {
        u16* Xbuf = (u16*)take(62914560);
        run_all<u16>(x, h0, Wz, Uz, Wr, Ur, Wh, Uh, Ua, Wa_w, Wa_b, fh_w, fh_b,
                     fb_w, fb_b, out, hbuf, zbuf, ua2, whi, wlo, xshi, xslo,
                     hhi, hlo, rhhi, rhlo, Xbuf, useXsLo, useWLo, stream);
    }
}

// Round 3
// 2557.417 us; speedup vs baseline: 3.7174x; 1.9728x over previous
//
#include <hip/hip_runtime.h>
#include <hip/hip_bf16.h>
#include <math.h>

#define BSZ 512
#define SEQL 32
#define EDIM 1024
#define HDIM 1024
#define MIDL 30

typedef unsigned short u16;
typedef __attribute__((ext_vector_type(8))) short bf16x8_t;   // 8 bf16 in 4 VGPRs
typedef __attribute__((ext_vector_type(4))) float floatx4_t;  // MFMA accumulator

// round-to-nearest bf16 split: v ~= hi + lo (each bf16), err ~2^-17 rel
__device__ inline u16 f2bf(float v) {
    unsigned u = __float_as_uint(v);
    unsigned r = u + 0x7FFFu + ((u >> 16) & 1u);
    return (u16)(r >> 16);
}
__device__ inline float bf2f(u16 h) { return __uint_as_float(((unsigned)h) << 16); }
__device__ inline void split2(float v, u16& hi, u16& lo) {
    u16 h = f2bf(v);
    hi = h;
    lo = f2bf(v - bf2f(h));
}

// LDS swizzle: row stride 128B, XOR row into 16B-slot bits (conflict-free b128)
#define SWZ(r, cb) (((r) << 7) + ((cb) ^ (((r) & 7) << 4)))

// async global->LDS, 16B per lane; LDS dest is wave-uniform base + lane*16
#define GLOAD16(g, l)                                                    \
    __builtin_amdgcn_global_load_lds(                                    \
        (const __attribute__((address_space(1))) void*)(g),              \
        (__attribute__((address_space(3))) void*)(l), 16, 0, 0)

// ---------------------------------------------------------------------------
__global__ __launch_bounds__(256) void convert_w(const float* __restrict__ src,
                                                 u16* __restrict__ hi,
                                                 u16* __restrict__ lo,
                                                 int writeLo) {
    size_t i = ((size_t)blockIdx.x * 256 + threadIdx.x) * 4;
    float4 v = *(const float4*)(src + i);
    u16 hx, lx, hy, ly, hz, lz, hw, lw;
    split2(v.x, hx, lx); split2(v.y, hy, ly);
    split2(v.z, hz, lz); split2(v.w, hw, lw);
    ushort4 hv; hv.x = hx; hv.y = hy; hv.z = hz; hv.w = hw;
    *(ushort4*)(hi + i) = hv;
    if (writeLo) {
        ushort4 lv; lv.x = lx; lv.y = ly; lv.z = lz; lv.w = lw;
        *(ushort4*)(lo + i) = lv;
    }
}

// ---------------------------------------------------------------------------
__global__ __launch_bounds__(256) void init_h(const float* __restrict__ h0,
                                              float* __restrict__ hbuf,
                                              u16* __restrict__ hhi,
                                              u16* __restrict__ hlo) {
    size_t i = ((size_t)blockIdx.x * 256 + threadIdx.x) * 4;
    float4 v = *(const float4*)(h0 + i);
    *(float4*)(hbuf + i) = v;
    u16 hx, lx, hy, ly, hz, lz, hw, lw;
    split2(v.x, hx, lx); split2(v.y, hy, ly);
    split2(v.z, hz, lz); split2(v.w, hw, lw);
    ushort4 hv; hv.x = hx; hv.y = hy; hv.z = hz; hv.w = hw;
    ushort4 lv; lv.x = lx; lv.y = ly; lv.z = lz; lv.w = lw;
    *(ushort4*)(hhi + i) = hv;
    *(ushort4*)(hlo + i) = lv;
}

// ---------------------------------------------------------------------------
__global__ __launch_bounds__(256) void xs_build(const float* __restrict__ x,
                                                u16* __restrict__ xshi,
                                                u16* __restrict__ xslo,
                                                int writeLo) {
    int idx = blockIdx.x * 256 + threadIdx.x;
    int vid = idx & 255;
    int bw = idx >> 8;
    int w = bw % 30, b = bw / 30;
    const float* s = x + ((size_t)b * SEQL + w) * EDIM + vid * 4;
    float4 a = *(const float4*)s;
    float4 c = *(const float4*)(s + EDIM);
    float4 e = *(const float4*)(s + 2 * EDIM);
    float4 v; v.x = a.x + c.x + e.x; v.y = a.y + c.y + e.y;
    v.z = a.z + c.z + e.z; v.w = a.w + c.w + e.w;
    size_t o = ((size_t)b * 30 + w) * EDIM + vid * 4;
    u16 hx, lx, hy, ly, hz, lz, hw, lw;
    split2(v.x, hx, lx); split2(v.y, hy, ly);
    split2(v.z, hz, lz); split2(v.w, hw, lw);
    ushort4 hv; hv.x = hx; hv.y = hy; hv.z = hz; hv.w = hw;
    *(ushort4*)(xshi + o) = hv;
    if (writeLo) {
        ushort4 lv; lv.x = lx; lv.y = ly; lv.z = lz; lv.w = lw;
        *(ushort4*)(xslo + o) = lv;
    }
}

// ---------------------------------------------------------------------------
__global__ __launch_bounds__(256) void ua2_kernel(const float* __restrict__ x,
                                                  const float* __restrict__ Ua,
                                                  float* __restrict__ ua2) {
    int bs = blockIdx.x;
    int b = bs >> 5, s = bs & 31;
    const float* xr = x + ((size_t)b * SEQL + s) * EDIM;
    int tid = threadIdx.x;
    float a[4] = {0.f, 0.f, 0.f, 0.f};
    for (int e = tid; e < EDIM; e += 256) {
        float xv = xr[e];
#pragma unroll
        for (int q = 0; q < 4; q++) a[q] += xv * Ua[q * EDIM + e];
    }
#pragma unroll
    for (int q = 0; q < 4; q++)
        for (int off = 32; off > 0; off >>= 1) a[q] += __shfl_down(a[q], off);
    __shared__ float sr[4][4];
    int wid = tid >> 6, lane = tid & 63;
    if (lane == 0) {
#pragma unroll
        for (int q = 0; q < 4; q++) sr[wid][q] = a[q];
    }
    __syncthreads();
    if (tid < 4) {
        float v = sr[0][tid] + sr[1][tid] + sr[2][tid] + sr[3][tid];
        int d = tid >> 1, h2 = tid & 1;
        ua2[(((size_t)d * BSZ + b) * SEQL + s) * 2 + h2] = v;
    }
}

// ---------------------------------------------------------------------------
// Fused per-step GEMM (bf16x3 MFMA, BMx64 tile, global_load_lds staging,
// XCD-chunked block swizzle) + (MODE0) attention blocks at blockIdx.y>=32.
// MODE0 (BM=64): A=[h|xs], B=[Uz|Wz]/[Ur|Wr]; z -> zbuf, r -> rh hi/lo
// MODE1 (BM=32): A=[rh|xs], B=[Uh|Wh]; h' = h + z*(tanh-h) -> hbuf + hi/lo
template<int BM, int MODE, typename XT>
__global__ __launch_bounds__(256) void gemm_step(
    const u16* __restrict__ whi, const u16* __restrict__ wlo,
    const u16* __restrict__ ahi, const u16* __restrict__ alo,
    const u16* __restrict__ xshi, const u16* __restrict__ xslo,
    float* __restrict__ hbuf, float* __restrict__ zbuf,
    u16* __restrict__ ohi, u16* __restrict__ olo,
    const float* __restrict__ x, const float* __restrict__ ua2,
    const float* __restrict__ Wa_w, const float* __restrict__ Wa_b,
    const float* __restrict__ fh_w, const float* __restrict__ fh_b,
    XT* __restrict__ Xbuf,
    int m, int useXsLo, int useWLo) {

    constexpr int MF = BM / 32;       // 16x16 m-frags per wave (2 or 1)
    constexpr int GX = 512 / BM;      // grid x extent

    __shared__ __align__(16) u16 AsHi[BM * 64], AsLo[BM * 64];
    __shared__ __align__(16) u16 BsHi[64 * 64], BsLo[64 * 64];
    __shared__ float sred[4][6];

    const int d = blockIdx.z;
    const int tid = threadIdx.x;
    const int wid = tid >> 6, lane = tid & 63;

    if (MODE == 0 && blockIdx.y >= 32) {
        // ------------------- attention path -------------------
        const int b = blockIdx.x * 64 + (blockIdx.y - 32);
        const float* hb = hbuf + ((size_t)d * BSZ + b) * HDIM;
        const float* Ww = Wa_w + (size_t)d * 6 * HDIM;
        float w6[6] = {0.f, 0.f, 0.f, 0.f, 0.f, 0.f};
        for (int j = tid; j < HDIM; j += 256) {
            float hv = hb[j];
#pragma unroll
            for (int q = 0; q < 6; q++) w6[q] += hv * Ww[q * HDIM + j];
        }
#pragma unroll
        for (int q = 0; q < 6; q++)
            for (int off = 32; off > 0; off >>= 1) w6[q] += __shfl_down(w6[q], off);
        if (lane == 0) {
#pragma unroll
            for (int q = 0; q < 6; q++) sred[wid][q] = w6[q];
        }
        __syncthreads();
        float s6[6];
#pragma unroll
        for (int q = 0; q < 6; q++)
            s6[q] = sred[0][q] + sred[1][q] + sred[2][q] + sred[3][q];

        int p0 = (d == 0) ? m : (31 - m);
        int p1 = (d == 0) ? (m + 1) : (30 - m);
        int p2 = (d == 0) ? (m + 2) : (29 - m);
        const float fw0 = fh_w[d * 2 + 0], fw1 = fh_w[d * 2 + 1], fbv = fh_b[d];
        float et[3];
        int pg[3] = {p0, p1, p2};
#pragma unroll
        for (int g = 0; g < 3; g++) {
            const float* u = ua2 + (((size_t)d * BSZ + b) * SEQL + pg[g]) * 2;
            float a0 = u[0] + s6[g] + Wa_b[d * 6 + g];
            float a1 = u[1] + s6[3 + g] + Wa_b[d * 6 + 3 + g];
            et[g] = tanhf(a0 * fw0 + a1 * fw1 + fbv);
        }
        float mx = fmaxf(et[0], fmaxf(et[1], et[2]));
        float e0 = expf(et[0] - mx), e1 = expf(et[1] - mx), e2 = expf(et[2] - mx);
        float inv = 1.f / (e0 + e1 + e2);
        float al0 = e0 * inv, al1 = e1 * inv, al2 = e2 * inv;

        const float* xb = x + (size_t)b * SEQL * EDIM;
        int e4 = tid * 4;
        float4 x0 = *(const float4*)(xb + (size_t)p0 * EDIM + e4);
        float4 x1 = *(const float4*)(xb + (size_t)p1 * EDIM + e4);
        float4 x2 = *(const float4*)(xb + (size_t)p2 * EDIM + e4);
        float4 v; v.x = al0 * x0.x + al1 * x1.x + al2 * x2.x;
        v.y = al0 * x0.y + al1 * x1.y + al2 * x2.y;
        v.z = al0 * x0.z + al1 * x1.z + al2 * x2.z;
        v.w = al0 * x0.w + al1 * x1.w + al2 * x2.w;
        XT* Xo = Xbuf + (((size_t)d * BSZ + b) * MIDL + m) * EDIM + e4;
        if constexpr (sizeof(XT) == 4) {
            *(float4*)Xo = v;
        } else {
            ushort4 uv; uv.x = f2bf(v.x); uv.y = f2bf(v.y);
            uv.z = f2bf(v.z); uv.w = f2bf(v.w);
            *(ushort4*)Xo = uv;
        }
        return;
    }

    // ------------------- GEMM path -------------------
    // bijective XCD chunk swizzle over the 256 works per z-slice
    const int lin = blockIdx.x + GX * blockIdx.y;
    const int work = (lin & 7) * 32 + (lin >> 3);
    const int b0 = (work & (GX - 1)) * BM;
    const int n0 = (work / GX) * 64;
    const int w = (d == 0) ? m : (29 - m);

    int rgate, nrow0, matU, matW;
    if (MODE == 0) {
        rgate = (n0 >= 1024) ? 1 : 0;
        nrow0 = n0 & 1023;
        matU = rgate ? 1 : 0;   // Uz=0, Ur=1
        matW = rgate ? 4 : 3;   // Wz=3, Wr=4
    } else {
        rgate = 0; nrow0 = n0; matU = 2; matW = 5;  // Uh=2, Wh=5
    }

    floatx4_t acc[MF][2];
#pragma unroll
    for (int i = 0; i < MF; i++)
#pragma unroll
        for (int j = 0; j < 2; j++) acc[i][j] = (floatx4_t){0.f, 0.f, 0.f, 0.f};

    const int wm = wid >> 1, wn = wid & 1;
    // per-lane pre-swizzled source slot (rule 21: src perm == read perm)
    const int rr = lane >> 3;                         // row within 8-row chunk
    const int swb = (((lane & 7) ^ rr) << 4);         // swizzled 16B slot (bytes)
    const int cA0 = wid, cA1 = wid + 4;               // A 8-row chunks per wave
    const int cB0 = wid, cB1 = wid + 4;               // B chunks per wave

    for (int half = 0; half < 2; half++) {
        const size_t wOff = (size_t)(half ? matW : matU) * 2097152 + (size_t)d * 1048576;
        const char* bH = (const char*)(whi + wOff);
        const char* bL = (const char*)(wlo + wOff);
        const int bLoOn = useWLo;
        int aLoOn;
        const char *pa0h, *pa0l, *pa1h = nullptr, *pa1l = nullptr;
        if (half == 0) {
            aLoOn = 1;   // h / rh always carry lo
            size_t r0 = (size_t)(d * BSZ + b0 + cA0 * 8 + rr) * 2048;
            pa0h = (const char*)ahi + r0 + swb;
            pa0l = (const char*)alo + r0 + swb;
            if (BM == 64) {
                size_t r1 = (size_t)(d * BSZ + b0 + cA1 * 8 + rr) * 2048;
                pa1h = (const char*)ahi + r1 + swb;
                pa1l = (const char*)alo + r1 + swb;
            }
        } else {
            aLoOn = useXsLo;
            size_t r0 = ((size_t)(b0 + cA0 * 8 + rr) * 30 + w) * 2048;
            pa0h = (const char*)xshi + r0 + swb;
            pa0l = (const char*)xslo + r0 + swb;
            if (BM == 64) {
                size_t r1 = ((size_t)(b0 + cA1 * 8 + rr) * 30 + w) * 2048;
                pa1h = (const char*)xshi + r1 + swb;
                pa1l = (const char*)xslo + r1 + swb;
            }
        }
        size_t q0 = (size_t)(nrow0 + cB0 * 8 + rr) * 2048;
        size_t q1 = (size_t)(nrow0 + cB1 * 8 + rr) * 2048;
        const char* pb0h = bH + q0 + swb;
        const char* pb1h = bH + q1 + swb;
        const char* pb0l = bL + q0 + swb;
        const char* pb1l = bL + q1 + swb;

        for (int kk = 0; kk < 16; kk++) {
            const size_t ko = (size_t)kk * 128;
            __syncthreads();   // previous tile fully consumed
            GLOAD16(pa0h + ko, (char*)AsHi + cA0 * 1024);
            if (BM == 64) GLOAD16(pa1h + ko, (char*)AsHi + cA1 * 1024);
            GLOAD16(pb0h + ko, (char*)BsHi + cB0 * 1024);
            GLOAD16(pb1h + ko, (char*)BsHi + cB1 * 1024);
            if (aLoOn) {
                GLOAD16(pa0l + ko, (char*)AsLo + cA0 * 1024);
                if (BM == 64) GLOAD16(pa1l + ko, (char*)AsLo + cA1 * 1024);
            }
            if (bLoOn) {
                GLOAD16(pb0l + ko, (char*)BsLo + cB0 * 1024);
                GLOAD16(pb1l + ko, (char*)BsLo + cB1 * 1024);
            }
            __syncthreads();   // vmcnt(0) drain -> LDS tile ready

#pragma unroll
            for (int cc = 0; cc < 2; cc++) {
                const int cbyte = cc * 64 + ((lane >> 4) << 4);
                bf16x8_t ah_[MF], al_[MF], bh_[2], bl_[2];
#pragma unroll
                for (int mf = 0; mf < MF; mf++) {
                    int r = wm * (BM / 2) + mf * 16 + (lane & 15);
                    int ia = SWZ(r, cbyte) >> 1;
                    ah_[mf] = *(const bf16x8_t*)(AsHi + ia);
                    if (aLoOn) al_[mf] = *(const bf16x8_t*)(AsLo + ia);
                }
#pragma unroll
                for (int nf = 0; nf < 2; nf++) {
                    int r = wn * 32 + nf * 16 + (lane & 15);
                    int ib = SWZ(r, cbyte) >> 1;
                    bh_[nf] = *(const bf16x8_t*)(BsHi + ib);
                    if (bLoOn) bl_[nf] = *(const bf16x8_t*)(BsLo + ib);
                }
#pragma unroll
                for (int mf = 0; mf < MF; mf++)
#pragma unroll
                    for (int nf = 0; nf < 2; nf++) {
                        acc[mf][nf] = __builtin_amdgcn_mfma_f32_16x16x32_bf16(
                            ah_[mf], bh_[nf], acc[mf][nf], 0, 0, 0);
                        if (bLoOn)
                            acc[mf][nf] = __builtin_amdgcn_mfma_f32_16x16x32_bf16(
                                ah_[mf], bl_[nf], acc[mf][nf], 0, 0, 0);
                        if (aLoOn)
                            acc[mf][nf] = __builtin_amdgcn_mfma_f32_16x16x32_bf16(
                                al_[mf], bh_[nf], acc[mf][nf], 0, 0, 0);
                    }
            }
        }
    }

    // epilogue: C/D layout col=lane&15, row=(lane>>4)*4+j
#pragma unroll
    for (int mf = 0; mf < MF; mf++)
#pragma unroll
        for (int nf = 0; nf < 2; nf++)
#pragma unroll
            for (int j = 0; j < 4; j++) {
                int bb = b0 + wm * (BM / 2) + mf * 16 + ((lane >> 4) << 2) + j;
                int nn = nrow0 + wn * 32 + nf * 16 + (lane & 15);
                size_t oi = ((size_t)d * BSZ + bb) * 1024 + nn;
                float v = acc[mf][nf][j];
                if (MODE == 0) {
                    float sg = 1.f / (1.f + expf(-v));
                    if (!rgate) {
                        zbuf[oi] = sg;
                    } else {
                        float rh = sg * hbuf[oi];
                        u16 h, l; split2(rh, h, l);
                        ohi[oi] = h; olo[oi] = l;
                    }
                } else {
                    float hw = tanhf(v);
                    float z = zbuf[oi], hv = hbuf[oi];
                    float hn = hv + z * (hw - hv);
                    hbuf[oi] = hn;
                    u16 h, l; split2(hn, h, l);
                    ohi[oi] = h; olo[oi] = l;
                }
            }
}

// ---------------------------------------------------------------------------
template<typename XT>
__global__ __launch_bounds__(256) void final_mix(const XT* __restrict__ Xbuf,
                                                 const float* __restrict__ fbw,
                                                 const float* __restrict__ fbb,
                                                 float* __restrict__ out) {
    __shared__ float sw[30][60];
    __shared__ float sb[30];
    const int tid = threadIdx.x;
    for (int i = tid; i < 1800; i += 256) sw[i / 60][i % 60] = fbw[i];
    if (tid < 30) sb[tid] = fbb[tid];
    __syncthreads();

    const int idx = blockIdx.x * 256 + tid;
    const int b = idx >> 10;
    const int e = idx & 1023;

    float accv[30];
#pragma unroll
    for (int mo = 0; mo < 30; mo++) accv[mo] = sb[mo];

    for (int dd = 0; dd < 2; dd++)
        for (int mm = 0; mm < 30; mm++) {
            float v;
            if constexpr (sizeof(XT) == 4)
                v = ((const float*)Xbuf)[(((size_t)dd * BSZ + b) * MIDL + mm) * EDIM + e];
            else
                v = bf2f(((const u16*)Xbuf)[(((size_t)dd * BSZ + b) * MIDL + mm) * EDIM + e]);
            int j = dd * 30 + mm;
#pragma unroll
            for (int mo = 0; mo < 30; mo++) accv[mo] += sw[mo][j] * v;
        }
    float* ob = out + (size_t)b * 30 * EDIM;
#pragma unroll
    for (int mo = 0; mo < 30; mo++) ob[(size_t)mo * EDIM + e] = accv[mo];
}

// ---------------------------------------------------------------------------
template<typename XT>
static void run_all(const float* x, const float* h0,
                    const float* Wz, const float* Uz, const float* Wr, const float* Ur,
                    const float* Wh, const float* Uh, const float* Ua,
                    const float* Wa_w, const float* Wa_b,
                    const float* fh_w, const float* fh_b,
                    const float* fb_w, const float* fb_b,
                    float* out,
                    float* hbuf, float* zbuf, float* ua2,
                    u16* whi, u16* wlo, u16* xshi, u16* xslo,
                    u16* hhi, u16* hlo, u16* rhhi, u16* rhlo,
                    XT* Xbuf, int useXsLo, int useWLo, hipStream_t stream) {
    convert_w<<<2048, 256, 0, stream>>>(Uz, whi + (size_t)0 * 2097152, wlo + (size_t)0 * 2097152, useWLo);
    convert_w<<<2048, 256, 0, stream>>>(Ur, whi + (size_t)1 * 2097152, wlo + (size_t)1 * 2097152, useWLo);
    convert_w<<<2048, 256, 0, stream>>>(Uh, whi + (size_t)2 * 2097152, wlo + (size_t)2 * 2097152, useWLo);
    convert_w<<<2048, 256, 0, stream>>>(Wz, whi + (size_t)3 * 2097152, wlo + (size_t)3 * 2097152, useWLo);
    convert_w<<<2048, 256, 0, stream>>>(Wr, whi + (size_t)4 * 2097152, wlo + (size_t)4 * 2097152, useWLo);
    convert_w<<<2048, 256, 0, stream>>>(Wh, whi + (size_t)5 * 2097152, wlo + (size_t)5 * 2097152, useWLo);
    init_h<<<1024, 256, 0, stream>>>(h0, hbuf, hhi, hlo);
    ua2_kernel<<<16384, 256, 0, stream>>>(x, Ua, ua2);
    xs_build<<<15360, 256, 0, stream>>>(x, xshi, xslo, useXsLo);

    for (int m = 0; m < MIDL; m++) {
        gemm_step<64, 0, XT><<<dim3(8, 32 + 64, 2), 256, 0, stream>>>(
            whi, wlo, hhi, hlo, xshi, xslo, hbuf, zbuf, rhhi, rhlo,
            x, ua2, Wa_w, Wa_b, fh_w, fh_b, Xbuf, m, useXsLo, useWLo);
        gemm_step<32, 1, XT><<<dim3(16, 16, 2), 256, 0, stream>>>(
            whi, wlo, rhhi, rhlo, xshi, xslo, hbuf, zbuf, hhi, hlo,
            x, ua2, Wa_w, Wa_b, fh_w, fh_b, Xbuf, m, useXsLo, useWLo);
    }
    final_mix<XT><<<2048, 256, 0, stream>>>(Xbuf, fb_w, fb_b, out);
}

extern "C" void kernel_launch(void* const* d_in, const int* in_sizes, int n_in,
                              void* d_out, int out_size, void* d_ws, size_t ws_size,
                              hipStream_t stream) {
    const float* x    = (const float*)d_in[0];
    const float* h0   = (const float*)d_in[1];
    const float* Wz   = (const float*)d_in[2];
    const float* Uz   = (const float*)d_in[3];
    const float* Wr   = (const float*)d_in[4];
    const float* Ur   = (const float*)d_in[5];
    const float* Wh   = (const float*)d_in[6];
    const float* Uh   = (const float*)d_in[7];
    const float* Ua   = (const float*)d_in[8];
    const float* Wa_w = (const float*)d_in[9];
    const float* Wa_b = (const float*)d_in[10];
    const float* fh_w = (const float*)d_in[11];
    const float* fh_b = (const float*)d_in[12];
    const float* fb_w = (const float*)d_in[13];
    const float* fb_b = (const float*)d_in[14];
    float* out = (float*)d_out;

    const size_t NEED1 = 256114688;   // fp32 Xbuf, full lo buffers
    const size_t NEED2 = 193200128;   // bf16 Xbuf, full lo buffers
    int useWLo = 1, useXsLo = 1;
    bool xf32 = (ws_size >= NEED1);
    bool tier3 = (!xf32 && ws_size < NEED2);
    if (tier3) { useWLo = 0; useXsLo = 0; }

    char* p = (char*)d_ws;
    auto take = [&](size_t n) { char* r = p; p += n; return r; };
    float* hbuf = (float*)take(4194304);
    float* zbuf = (float*)take(4194304);
    float* ua2  = (float*)take(262144);
    u16* whi  = (u16*)take(25165824);
    u16* wlo  = useWLo ? (u16*)take(25165824) : whi;
    u16* xshi = (u16*)take(31457280);
    u16* xslo = useXsLo ? (u16*)take(31457280) : xshi;
    u16* hhi  = (u16*)take(2097152);
    u16* hlo  = (u16*)take(2097152);
    u16* rhhi = (u16*)take(2097152);
    u16* rhlo = (u16*)take(2097152);

    if (xf32) {
        float* Xbuf = (float*)take(125829120);
        run_all<float>(x, h0, Wz, Uz, Wr, Ur, Wh, Uh, Ua, Wa_w, Wa_b, fh_w, fh_b,
                       fb_w, fb_b, out, hbuf, zbuf, ua2, whi, wlo, xshi, xslo,
                       hhi, hlo, rhhi, rhlo, Xbuf, useXsLo, useWLo, stream);
    } else {
        u16* Xbuf = (u16*)take(62914560);
        run_all<u16>(x, h0, Wz, Uz, Wr, Ur, Wh, Uh, Ua, Wa_w, Wa_b, fh_w, fh_b,
                     fb_w, fb_b, out, hbuf, zbuf, ua2, whi, wlo, xshi, xslo,
                     hhi, hlo, rhhi, rhlo, Xbuf, useXsLo, useWLo, stream);
    }
}

// Round 5
// 2476.609 us; speedup vs baseline: 3.8387x; 1.0326x over previous
//
#include <hip/hip_runtime.h>
#include <hip/hip_bf16.h>
#include <math.h>

#define BSZ 512
#define SEQL 32
#define EDIM 1024
#define HDIM 1024
#define MIDL 30

typedef unsigned short u16;
typedef _Float16 f16;
typedef __attribute__((ext_vector_type(8))) _Float16 f16x8_t;  // 8 fp16 in 4 VGPRs
typedef __attribute__((ext_vector_type(4))) float floatx4_t;   // MFMA accumulator

__device__ inline u16 f2bf(float v) {
    unsigned u = __float_as_uint(v);
    unsigned r = u + 0x7FFFu + ((u >> 16) & 1u);
    return (u16)(r >> 16);
}
__device__ inline float bf2f(u16 h) { return __uint_as_float(((unsigned)h) << 16); }

__device__ inline u16 f2h(float v) {
    f16 h = (f16)v; u16 r; __builtin_memcpy(&r, &h, 2); return r;
}
// fp16 split: v ~= hi + lo, combined ~2^-22 rel err
__device__ inline void splith(float v, u16& hi, u16& lo) {
    f16 h = (f16)v;
    f16 l = (f16)(v - (float)h);
    __builtin_memcpy(&hi, &h, 2);
    __builtin_memcpy(&lo, &l, 2);
}

// LDS swizzle: row stride 128B, XOR row into 16B-slot bits (conflict-free b128)
#define SWZ(r, cb) (((r) << 7) + ((cb) ^ (((r) & 7) << 4)))

// async global->LDS, 16B per lane; LDS dest is wave-uniform base + lane*16
#define GLOAD16(g, l)                                                    \
    __builtin_amdgcn_global_load_lds(                                    \
        (const __attribute__((address_space(1))) void*)(g),              \
        (__attribute__((address_space(3))) void*)(l), 16, 0, 0)

// ---------------------------------------------------------------------------
// all 6 weight matrices fp32 -> fp16 in one kernel. order: Uz,Ur,Uh,Wz,Wr,Wh
__global__ __launch_bounds__(256) void convert_w6(
    const float* __restrict__ s0, const float* __restrict__ s1,
    const float* __restrict__ s2, const float* __restrict__ s3,
    const float* __restrict__ s4, const float* __restrict__ s5,
    u16* __restrict__ whi) {
    int mat = blockIdx.x >> 11;
    const float* src = (mat == 0) ? s0 : (mat == 1) ? s1 : (mat == 2) ? s2
                     : (mat == 3) ? s3 : (mat == 4) ? s4 : s5;
    size_t i = ((size_t)(blockIdx.x & 2047) * 256 + threadIdx.x) * 4;
    float4 v = *(const float4*)(src + i);
    ushort4 hv; hv.x = f2h(v.x); hv.y = f2h(v.y); hv.z = f2h(v.z); hv.w = f2h(v.w);
    *(ushort4*)(whi + (size_t)mat * 2097152 + i) = hv;
}

// ---------------------------------------------------------------------------
__global__ __launch_bounds__(256) void init_h(const float* __restrict__ h0,
                                              float* __restrict__ hbuf,
                                              u16* __restrict__ hhi,
                                              u16* __restrict__ hlo) {
    size_t i = ((size_t)blockIdx.x * 256 + threadIdx.x) * 4;
    float4 v = *(const float4*)(h0 + i);
    *(float4*)(hbuf + i) = v;
    u16 hx, lx, hy, ly, hz, lz, hw, lw;
    splith(v.x, hx, lx); splith(v.y, hy, ly);
    splith(v.z, hz, lz); splith(v.w, hw, lw);
    ushort4 hv; hv.x = hx; hv.y = hy; hv.z = hz; hv.w = hw;
    ushort4 lv; lv.x = lx; lv.y = ly; lv.z = lz; lv.w = lw;
    *(ushort4*)(hhi + i) = hv;
    *(ushort4*)(hlo + i) = lv;
}

// ---------------------------------------------------------------------------
// xs_win[b][w][e] = sum of 3 x rows -> fp16 (single)
__global__ __launch_bounds__(256) void xs_build(const float* __restrict__ x,
                                                u16* __restrict__ xshi) {
    int idx = blockIdx.x * 256 + threadIdx.x;
    int vid = idx & 255;
    int bw = idx >> 8;
    int w = bw % 30, b = bw / 30;
    const float* s = x + ((size_t)b * SEQL + w) * EDIM + vid * 4;
    float4 a = *(const float4*)s;
    float4 c = *(const float4*)(s + EDIM);
    float4 e = *(const float4*)(s + 2 * EDIM);
    float4 v; v.x = a.x + c.x + e.x; v.y = a.y + c.y + e.y;
    v.z = a.z + c.z + e.z; v.w = a.w + c.w + e.w;
    size_t o = ((size_t)b * 30 + w) * EDIM + vid * 4;
    ushort4 hv; hv.x = f2h(v.x); hv.y = f2h(v.y); hv.z = f2h(v.z); hv.w = f2h(v.w);
    *(ushort4*)(xshi + o) = hv;
}

// ---------------------------------------------------------------------------
__global__ __launch_bounds__(256) void ua2_kernel(const float* __restrict__ x,
                                                  const float* __restrict__ Ua,
                                                  float* __restrict__ ua2) {
    int bs = blockIdx.x;
    int b = bs >> 5, s = bs & 31;
    const float* xr = x + ((size_t)b * SEQL + s) * EDIM;
    int tid = threadIdx.x;
    float a[4] = {0.f, 0.f, 0.f, 0.f};
    for (int e = tid; e < EDIM; e += 256) {
        float xv = xr[e];
#pragma unroll
        for (int q = 0; q < 4; q++) a[q] += xv * Ua[q * EDIM + e];
    }
#pragma unroll
    for (int q = 0; q < 4; q++)
        for (int off = 32; off > 0; off >>= 1) a[q] += __shfl_down(a[q], off);
    __shared__ float sr[4][4];
    int wid = tid >> 6, lane = tid & 63;
    if (lane == 0) {
#pragma unroll
        for (int q = 0; q < 4; q++) sr[wid][q] = a[q];
    }
    __syncthreads();
    if (tid < 4) {
        float v = sr[0][tid] + sr[1][tid] + sr[2][tid] + sr[3][tid];
        int d = tid >> 1, h2 = tid & 1;
        ua2[(((size_t)d * BSZ + b) * SEQL + s) * 2 + h2] = v;
    }
}

// ---------------------------------------------------------------------------
// Fused per-step GEMM (fp16 MFMA: A = hi+lo for state half, single for xs
// half; B = fp16 weights) with 2-phase double-buffered pipeline.
// MODE0 (BM=64): A=[h|xs], B=[Uz|Wz]/[Ur|Wr]; z -> zbuf, r -> rh hi/lo.
//                blockIdx.y >= 32 -> attention blocks.
// MODE1 (BM=32): A=[rh|xs], B=[Uh|Wh]; h' = h + z*(tanh-h) -> hbuf + hi/lo
template<int BM, int MODE, typename XT>
__global__ __launch_bounds__(256) void gemm_step(
    const u16* __restrict__ whi,
    const u16* __restrict__ ahi, const u16* __restrict__ alo,
    const u16* __restrict__ xshi,
    float* __restrict__ hbuf, float* __restrict__ zbuf,
    u16* __restrict__ ohi, u16* __restrict__ olo,
    const float* __restrict__ x, const float* __restrict__ ua2,
    const float* __restrict__ Wa_w, const float* __restrict__ Wa_b,
    const float* __restrict__ fh_w, const float* __restrict__ fh_b,
    XT* __restrict__ Xbuf, int m) {

    constexpr int MF = BM / 32;
    constexpr int GX = 512 / BM;

    __shared__ __align__(16) u16 AsH[2][BM * 64];
    __shared__ __align__(16) u16 AsL[2][BM * 64];
    __shared__ __align__(16) u16 BsH[2][64 * 64];
    __shared__ float sred[4][6];

    const int d = blockIdx.z;
    const int tid = threadIdx.x;
    const int wid = tid >> 6, lane = tid & 63;

    if (MODE == 0 && blockIdx.y >= 32) {
        // ------------------- attention path -------------------
        const int b = blockIdx.x * 64 + (blockIdx.y - 32);
        const float* hb = hbuf + ((size_t)d * BSZ + b) * HDIM;
        const float* Ww = Wa_w + (size_t)d * 6 * HDIM;
        float w6[6] = {0.f, 0.f, 0.f, 0.f, 0.f, 0.f};
        for (int j = tid; j < HDIM; j += 256) {
            float hv = hb[j];
#pragma unroll
            for (int q = 0; q < 6; q++) w6[q] += hv * Ww[q * HDIM + j];
        }
#pragma unroll
        for (int q = 0; q < 6; q++)
            for (int off = 32; off > 0; off >>= 1) w6[q] += __shfl_down(w6[q], off);
        if (lane == 0) {
#pragma unroll
            for (int q = 0; q < 6; q++) sred[wid][q] = w6[q];
        }
        __syncthreads();
        float s6[6];
#pragma unroll
        for (int q = 0; q < 6; q++)
            s6[q] = sred[0][q] + sred[1][q] + sred[2][q] + sred[3][q];

        int p0 = (d == 0) ? m : (31 - m);
        int p1 = (d == 0) ? (m + 1) : (30 - m);
        int p2 = (d == 0) ? (m + 2) : (29 - m);
        const float fw0 = fh_w[d * 2 + 0], fw1 = fh_w[d * 2 + 1], fbv = fh_b[d];
        float et[3];
        int pg[3] = {p0, p1, p2};
#pragma unroll
        for (int g = 0; g < 3; g++) {
            const float* u = ua2 + (((size_t)d * BSZ + b) * SEQL + pg[g]) * 2;
            float a0 = u[0] + s6[g] + Wa_b[d * 6 + g];
            float a1 = u[1] + s6[3 + g] + Wa_b[d * 6 + 3 + g];
            et[g] = tanhf(a0 * fw0 + a1 * fw1 + fbv);
        }
        float mx = fmaxf(et[0], fmaxf(et[1], et[2]));
        float e0 = expf(et[0] - mx), e1 = expf(et[1] - mx), e2 = expf(et[2] - mx);
        float inv = 1.f / (e0 + e1 + e2);
        float al0 = e0 * inv, al1 = e1 * inv, al2 = e2 * inv;

        const float* xb = x + (size_t)b * SEQL * EDIM;
        int e4 = tid * 4;
        float4 x0 = *(const float4*)(xb + (size_t)p0 * EDIM + e4);
        float4 x1 = *(const float4*)(xb + (size_t)p1 * EDIM + e4);
        float4 x2 = *(const float4*)(xb + (size_t)p2 * EDIM + e4);
        float4 v; v.x = al0 * x0.x + al1 * x1.x + al2 * x2.x;
        v.y = al0 * x0.y + al1 * x1.y + al2 * x2.y;
        v.z = al0 * x0.z + al1 * x1.z + al2 * x2.z;
        v.w = al0 * x0.w + al1 * x1.w + al2 * x2.w;
        XT* Xo = Xbuf + (((size_t)d * BSZ + b) * MIDL + m) * EDIM + e4;
        if constexpr (sizeof(XT) == 4) {
            *(float4*)Xo = v;
        } else {
            ushort4 uv; uv.x = f2bf(v.x); uv.y = f2bf(v.y);
            uv.z = f2bf(v.z); uv.w = f2bf(v.w);
            *(ushort4*)Xo = uv;
        }
        return;
    }

    // ------------------- GEMM path -------------------
    const int lin = blockIdx.x + GX * blockIdx.y;
    const int work = (lin & 7) * 32 + (lin >> 3);   // bijective XCD chunk swizzle
    const int b0 = (work & (GX - 1)) * BM;
    const int n0 = (work / GX) * 64;
    const int w = (d == 0) ? m : (29 - m);

    int rgate, nrow0, matU, matW;
    if (MODE == 0) {
        rgate = (n0 >= 1024) ? 1 : 0;
        nrow0 = n0 & 1023;
        matU = rgate ? 1 : 0;   // Uz=0, Ur=1
        matW = rgate ? 4 : 3;   // Wz=3, Wr=4
    } else {
        rgate = 0; nrow0 = n0; matU = 2; matW = 5;  // Uh=2, Wh=5
    }

    floatx4_t acc[MF][2];
#pragma unroll
    for (int i = 0; i < MF; i++)
#pragma unroll
        for (int j = 0; j < 2; j++) acc[i][j] = (floatx4_t){0.f, 0.f, 0.f, 0.f};

    const int wm = wid >> 1, wn = wid & 1;
    const int rr = lane >> 3;
    const int swb = (((lane & 7) ^ rr) << 4);   // pre-swizzled 16B slot
    const int cA0 = wid, cA1 = wid + 4;
    const int cB0 = wid, cB1 = wid + 4;

    // per-half base pointers (bytes); row stride 2048 B (1024 fp16)
    const u16* bU = whi + (size_t)matU * 2097152 + (size_t)d * 1048576;
    const u16* bW = whi + (size_t)matW * 2097152 + (size_t)d * 1048576;
    size_t ar0 = (size_t)(d * BSZ + b0 + cA0 * 8 + rr) * 2048;
    size_t ar1 = (size_t)(d * BSZ + b0 + cA1 * 8 + rr) * 2048;
    const char* pa0h = (const char*)ahi + ar0 + swb;
    const char* pa0l = (const char*)alo + ar0 + swb;
    const char* pa1h = (const char*)ahi + ar1 + swb;
    const char* pa1l = (const char*)alo + ar1 + swb;
    size_t xr0 = ((size_t)(b0 + cA0 * 8 + rr) * 30 + w) * 2048;
    size_t xr1 = ((size_t)(b0 + cA1 * 8 + rr) * 30 + w) * 2048;
    const char* px0 = (const char*)xshi + xr0 + swb;
    const char* px1 = (const char*)xshi + xr1 + swb;
    size_t q0 = (size_t)(nrow0 + cB0 * 8 + rr) * 2048;
    size_t q1 = (size_t)(nrow0 + cB1 * 8 + rr) * 2048;
    const char* pbU0 = (const char*)bU + q0 + swb;
    const char* pbU1 = (const char*)bU + q1 + swb;
    const char* pbW0 = (const char*)bW + q0 + swb;
    const char* pbW1 = (const char*)bW + q1 + swb;

    auto STAGE = [&](int kt, int pb) {
        const size_t ko = (size_t)(kt & 15) * 128;
        char* ah = (char*)AsH[pb];
        char* al = (char*)AsL[pb];
        char* bs = (char*)BsH[pb];
        if (kt < 16) {
            GLOAD16(pa0h + ko, ah + cA0 * 1024);
            if constexpr (BM == 64) GLOAD16(pa1h + ko, ah + cA1 * 1024);
            GLOAD16(pa0l + ko, al + cA0 * 1024);
            if constexpr (BM == 64) GLOAD16(pa1l + ko, al + cA1 * 1024);
            GLOAD16(pbU0 + ko, bs + cB0 * 1024);
            GLOAD16(pbU1 + ko, bs + cB1 * 1024);
        } else {
            GLOAD16(px0 + ko, ah + cA0 * 1024);
            if constexpr (BM == 64) GLOAD16(px1 + ko, ah + cA1 * 1024);
            GLOAD16(pbW0 + ko, bs + cB0 * 1024);
            GLOAD16(pbW1 + ko, bs + cB1 * 1024);
        }
    };

    auto COMPUTE = [&](int kt, int pb) {
        const bool hasLo = (kt < 16);
#pragma unroll
        for (int cc = 0; cc < 2; cc++) {
            const int cbyte = cc * 64 + ((lane >> 4) << 4);
            f16x8_t ah_[MF], al_[MF], bh_[2];
#pragma unroll
            for (int mf = 0; mf < MF; mf++) {
                int r = wm * (BM / 2) + mf * 16 + (lane & 15);
                int ia = SWZ(r, cbyte) >> 1;
                ah_[mf] = *(const f16x8_t*)(AsH[pb] + ia);
                if (hasLo) al_[mf] = *(const f16x8_t*)(AsL[pb] + ia);
            }
#pragma unroll
            for (int nf = 0; nf < 2; nf++) {
                int r = wn * 32 + nf * 16 + (lane & 15);
                int ib = SWZ(r, cbyte) >> 1;
                bh_[nf] = *(const f16x8_t*)(BsH[pb] + ib);
            }
#pragma unroll
            for (int mf = 0; mf < MF; mf++)
#pragma unroll
                for (int nf = 0; nf < 2; nf++) {
                    acc[mf][nf] = __builtin_amdgcn_mfma_f32_16x16x32_f16(
                        ah_[mf], bh_[nf], acc[mf][nf], 0, 0, 0);
                    if (hasLo)
                        acc[mf][nf] = __builtin_amdgcn_mfma_f32_16x16x32_f16(
                            al_[mf], bh_[nf], acc[mf][nf], 0, 0, 0);
                }
        }
    };

    // 2-phase pipeline: stage(t+1) in flight while computing t
    STAGE(0, 0);
    __syncthreads();
    int cur = 0;
    for (int kt = 0; kt < 31; kt++) {
        STAGE(kt + 1, cur ^ 1);
        COMPUTE(kt, cur);
        __syncthreads();
        cur ^= 1;
    }
    COMPUTE(31, cur);

    // epilogue: C/D layout col=lane&15, row=(lane>>4)*4+j
#pragma unroll
    for (int mf = 0; mf < MF; mf++)
#pragma unroll
        for (int nf = 0; nf < 2; nf++)
#pragma unroll
            for (int j = 0; j < 4; j++) {
                int bb = b0 + wm * (BM / 2) + mf * 16 + ((lane >> 4) << 2) + j;
                int nn = nrow0 + wn * 32 + nf * 16 + (lane & 15);
                size_t oi = ((size_t)d * BSZ + bb) * 1024 + nn;
                float v = acc[mf][nf][j];
                if (MODE == 0) {
                    float sg = 1.f / (1.f + expf(-v));
                    if (!rgate) {
                        zbuf[oi] = sg;
                    } else {
                        float rh = sg * hbuf[oi];
                        u16 h, l; splith(rh, h, l);
                        ohi[oi] = h; olo[oi] = l;
                    }
                } else {
                    float hw = tanhf(v);
                    float z = zbuf[oi], hv = hbuf[oi];
                    float hn = hv + z * (hw - hv);
                    hbuf[oi] = hn;
                    u16 h, l; splith(hn, h, l);
                    ohi[oi] = h; olo[oi] = l;
                }
            }
}

// ---------------------------------------------------------------------------
// out[b,mo,e] = sum_j fb_w[mo,j]*Xcat[b,j,e] + fb_b[mo]; float2 per thread
template<typename XT>
__global__ __launch_bounds__(256) void final_mix(const XT* __restrict__ Xbuf,
                                                 const float* __restrict__ fbw,
                                                 const float* __restrict__ fbb,
                                                 float* __restrict__ out) {
    __shared__ float sw[60][30];   // [j][mo]
    __shared__ float sb[30];
    const int tid = threadIdx.x;
    for (int i = tid; i < 1800; i += 256) {
        int mo = i / 60, j = i % 60;
        sw[j][mo] = fbw[i];
    }
    if (tid < 30) sb[tid] = fbb[tid];
    __syncthreads();

    const int idx = blockIdx.x * 256 + tid;   // 0..262143
    const int b = idx >> 9;
    const int e2 = (idx & 511) * 2;

    float2 acc[30];
#pragma unroll
    for (int mo = 0; mo < 30; mo++) { acc[mo].x = sb[mo]; acc[mo].y = sb[mo]; }

    for (int dd = 0; dd < 2; dd++)
#pragma unroll 2
        for (int mm = 0; mm < 30; mm++) {
            float2 v;
            if constexpr (sizeof(XT) == 4) {
                v = *(const float2*)((const float*)Xbuf +
                    (((size_t)dd * BSZ + b) * MIDL + mm) * EDIM + e2);
            } else {
                const u16* s = (const u16*)Xbuf +
                    (((size_t)dd * BSZ + b) * MIDL + mm) * EDIM + e2;
                v.x = bf2f(s[0]); v.y = bf2f(s[1]);
            }
            int j = dd * 30 + mm;
#pragma unroll
            for (int mo = 0; mo < 30; mo++) {
                acc[mo].x += sw[j][mo] * v.x;
                acc[mo].y += sw[j][mo] * v.y;
            }
        }
    float* ob = out + (size_t)b * 30 * EDIM + e2;
#pragma unroll
    for (int mo = 0; mo < 30; mo++) *(float2*)(ob + (size_t)mo * EDIM) = acc[mo];
}

// ---------------------------------------------------------------------------
template<typename XT>
static void run_all(const float* x, const float* h0,
                    const float* Wz, const float* Uz, const float* Wr, const float* Ur,
                    const float* Wh, const float* Uh, const float* Ua,
                    const float* Wa_w, const float* Wa_b,
                    const float* fh_w, const float* fh_b,
                    const float* fb_w, const float* fb_b,
                    float* out,
                    float* hbuf, float* zbuf, float* ua2,
                    u16* whi, u16* xshi,
                    u16* hhi, u16* hlo, u16* rhhi, u16* rhlo,
                    XT* Xbuf, hipStream_t stream) {
    convert_w6<<<12288, 256, 0, stream>>>(Uz, Ur, Uh, Wz, Wr, Wh, whi);
    init_h<<<1024, 256, 0, stream>>>(h0, hbuf, hhi, hlo);
    ua2_kernel<<<16384, 256, 0, stream>>>(x, Ua, ua2);
    xs_build<<<15360, 256, 0, stream>>>(x, xshi);

    for (int m = 0; m < MIDL; m++) {
        gemm_step<64, 0, XT><<<dim3(8, 32 + 64, 2), 256, 0, stream>>>(
            whi, hhi, hlo, xshi, hbuf, zbuf, rhhi, rhlo,
            x, ua2, Wa_w, Wa_b, fh_w, fh_b, Xbuf, m);
        gemm_step<32, 1, XT><<<dim3(16, 16, 2), 256, 0, stream>>>(
            whi, rhhi, rhlo, xshi, hbuf, zbuf, hhi, hlo,
            x, ua2, Wa_w, Wa_b, fh_w, fh_b, Xbuf, m);
    }
    final_mix<XT><<<1024, 256, 0, stream>>>(Xbuf, fb_w, fb_b, out);
}

extern "C" void kernel_launch(void* const* d_in, const int* in_sizes, int n_in,
                              void* d_out, int out_size, void* d_ws, size_t ws_size,
                              hipStream_t stream) {
    const float* x    = (const float*)d_in[0];
    const float* h0   = (const float*)d_in[1];
    const float* Wz   = (const float*)d_in[2];
    const float* Uz   = (const float*)d_in[3];
    const float* Wr   = (const float*)d_in[4];
    const float* Ur   = (const float*)d_in[5];
    const float* Wh   = (const float*)d_in[6];
    const float* Uh   = (const float*)d_in[7];
    const float* Ua   = (const float*)d_in[8];
    const float* Wa_w = (const float*)d_in[9];
    const float* Wa_b = (const float*)d_in[10];
    const float* fh_w = (const float*)d_in[11];
    const float* fh_b = (const float*)d_in[12];
    const float* fb_w = (const float*)d_in[13];
    const float* fb_b = (const float*)d_in[14];
    float* out = (float*)d_out;

    const size_t NEED1 = 199491584;   // fp32 Xbuf tier
    bool xf32 = (ws_size >= NEED1);

    char* p = (char*)d_ws;
    auto take = [&](size_t n) { char* r = p; p += n; return r; };
    float* hbuf = (float*)take(4194304);
    float* zbuf = (float*)take(4194304);
    float* ua2  = (float*)take(262144);
    u16* whi  = (u16*)take(25165824);    // 6 matrices fp16
    u16* xshi = (u16*)take(31457280);
    u16* hhi  = (u16*)take(2097152);
    u16* hlo  = (u16*)take(2097152);
    u16* rhhi = (u16*)take(2097152);
    u16* rhlo = (u16*)take(2097152);

    if (xf32) {
        float* Xbuf = (float*)take(125829120);
        run_all<float>(x, h0, Wz, Uz, Wr, Ur, Wh, Uh, Ua, Wa_w, Wa_b, fh_w, fh_b,
                       fb_w, fb_b, out, hbuf, zbuf, ua2, whi, xshi,
                       hhi, hlo, rhhi, rhlo, Xbuf, stream);
    } else {
        u16* Xbuf = (u16*)take(62914560);
        run_all<u16>(x, h0, Wz, Uz, Wr, Ur, Wh, Uh, Ua, Wa_w, Wa_b, fh_w, fh_b,
                     fb_w, fb_b, out, hbuf, zbuf, ua2, whi, xshi,
                     hhi, hlo, rhhi, rhlo, Xbuf, stream);
    }
}